// Round 5
// baseline (155.371 us; speedup 1.0000x reference)
//
#include <hip/hip_runtime.h>

#define N_NODES 50000
#define N_EDGES 800000
#define IN_SIZE 128
#define OUT_SIZE 64
#define BIN_CAP 64   // max edges per row; Poisson(16) => P(>=64) ~ 2e-18

// GEMM tiling
#define BM 128       // rows per block
#define KC 32        // k-chunk staged in LDS
#define KPAD 36      // row stride in LDS floats (16B-aligned, bank-offset 4)

// -------------------------------------------------------------------------
// Kernel 1: support[N,64] = x[N,128] @ weight[128,64]
// Register-blocked: 256 thr, thread tile 8 rows x 4 cols (rows rg+16i, cols
// (tid>>4)*4..+3). x per-K-chunk in LDS via coalesced per-lane float4 loads
// with register prefetch; w staged once in K-chunked LDS (bank-analyzed).
// -------------------------------------------------------------------------
__global__ __launch_bounds__(256) void gemm_xw(const float* __restrict__ x,
                                               const float* __restrict__ w,
                                               float* __restrict__ support) {
    __shared__ float xs[BM][KPAD];               // 18.4 KB
    __shared__ float wt[4][OUT_SIZE][KPAD];      // 36.9 KB  wt[kc][c][k&31] = w[k][c]
    const int tid  = threadIdx.x;
    const int row0 = blockIdx.x * BM;

    // ---- stage full weight once: thread covers float4 f = tid + 256*i ----
    #pragma unroll
    for (int i = 0; i < 8; ++i) {
        const int f  = tid + 256 * i;            // f < 2048
        const int k  = f >> 4;                   // 0..127
        const int c0 = (f & 15) << 2;            // 0..60
        const float4 wv = ((const float4*)w)[f];
        wt[k >> 5][c0 + 0][k & 31] = wv.x;
        wt[k >> 5][c0 + 1][k & 31] = wv.y;
        wt[k >> 5][c0 + 2][k & 31] = wv.z;
        wt[k >> 5][c0 + 3][k & 31] = wv.w;
    }

    // ---- prefetch x chunk 0 into registers (coalesced per-lane) ----
    float4 xreg[4];
    #pragma unroll
    for (int i = 0; i < 4; ++i) {
        const int f = tid + 256 * i;             // f < 1024: row=f>>3, koff=(f&7)*4
        int r = row0 + (f >> 3);
        if (r >= N_NODES) r = N_NODES - 1;       // clamp (garbage rows unused)
        xreg[i] = *(const float4*)(x + (long)r * IN_SIZE + ((f & 7) << 2));
    }

    const int rg = tid & 15;                     // rows rg + 16*i
    const int c0 = (tid >> 4) << 2;              // cols c0..c0+3
    float4 acc[8];
    #pragma unroll
    for (int i = 0; i < 8; ++i) acc[i] = make_float4(0.f, 0.f, 0.f, 0.f);

    for (int kc = 0; kc < 4; ++kc) {
        __syncthreads();
        // regs -> LDS
        #pragma unroll
        for (int i = 0; i < 4; ++i) {
            const int f = tid + 256 * i;
            *(float4*)&xs[f >> 3][(f & 7) << 2] = xreg[i];
        }
        __syncthreads();
        // issue next chunk's loads before compute (latency hides under FMAs)
        if (kc < 3) {
            #pragma unroll
            for (int i = 0; i < 4; ++i) {
                const int f = tid + 256 * i;
                int r = row0 + (f >> 3);
                if (r >= N_NODES) r = N_NODES - 1;
                xreg[i] = *(const float4*)(x + (long)r * IN_SIZE + (kc + 1) * KC + ((f & 7) << 2));
            }
        }
        // compute this chunk
        #pragma unroll
        for (int k4 = 0; k4 < 8; ++k4) {
            const float4 w0 = *(const float4*)&wt[kc][c0 + 0][k4 << 2];
            const float4 w1 = *(const float4*)&wt[kc][c0 + 1][k4 << 2];
            const float4 w2 = *(const float4*)&wt[kc][c0 + 2][k4 << 2];
            const float4 w3 = *(const float4*)&wt[kc][c0 + 3][k4 << 2];
            #pragma unroll
            for (int i = 0; i < 8; ++i) {
                const float4 xv = *(const float4*)&xs[rg + (i << 4)][k4 << 2];
                acc[i].x += xv.x * w0.x + xv.y * w0.y + xv.z * w0.z + xv.w * w0.w;
                acc[i].y += xv.x * w1.x + xv.y * w1.y + xv.z * w1.z + xv.w * w1.w;
                acc[i].z += xv.x * w2.x + xv.y * w2.y + xv.z * w2.z + xv.w * w2.w;
                acc[i].w += xv.x * w3.x + xv.y * w3.y + xv.z * w3.z + xv.w * w3.w;
            }
        }
    }

    #pragma unroll
    for (int i = 0; i < 8; ++i) {
        const int r = row0 + rg + (i << 4);
        if (r < N_NODES)
            *(float4*)(support + (long)r * OUT_SIZE + c0) = acc[i];
    }
}

// -------------------------------------------------------------------------
// Kernel 2: bin (col,val) by destination row. cnt stride = 1<<cs_shift ints
// (line-padded counters kill same-line atomic ping-pong).
// -------------------------------------------------------------------------
__global__ __launch_bounds__(256) void bin_edges_pay(const int* __restrict__ rows,
                                                     const int* __restrict__ cols,
                                                     const float* __restrict__ vals,
                                                     int* __restrict__ cnt,
                                                     int2* __restrict__ pay,
                                                     int cs_shift) {
    const int i  = blockIdx.x * 256 + threadIdx.x;
    const int e0 = i * 4;
    if (e0 + 4 <= N_EDGES) {
        const int4   r4 = ((const int4*)rows)[i];
        const int4   c4 = ((const int4*)cols)[i];
        const float4 v4 = ((const float4*)vals)[i];
        int s;
        s = atomicAdd(&cnt[r4.x << cs_shift], 1); if (s < BIN_CAP) pay[r4.x * BIN_CAP + s] = make_int2(c4.x, __float_as_int(v4.x));
        s = atomicAdd(&cnt[r4.y << cs_shift], 1); if (s < BIN_CAP) pay[r4.y * BIN_CAP + s] = make_int2(c4.y, __float_as_int(v4.y));
        s = atomicAdd(&cnt[r4.z << cs_shift], 1); if (s < BIN_CAP) pay[r4.z * BIN_CAP + s] = make_int2(c4.z, __float_as_int(v4.z));
        s = atomicAdd(&cnt[r4.w << cs_shift], 1); if (s < BIN_CAP) pay[r4.w * BIN_CAP + s] = make_int2(c4.w, __float_as_int(v4.w));
    } else {
        for (int e = e0; e < N_EDGES; ++e) {
            const int r = rows[e];
            const int s = atomicAdd(&cnt[r << cs_shift], 1);
            if (s < BIN_CAP) pay[r * BIN_CAP + s] = make_int2(cols[e], __float_as_int(vals[e]));
        }
    }
}

// -------------------------------------------------------------------------
// Kernel 3: per-row gather-reduce, ILP-pipelined (8-deep).
// -------------------------------------------------------------------------
__global__ __launch_bounds__(256) void reduce_rows_pay(const float* __restrict__ support,
                                                       const int* __restrict__ cnt,
                                                       const int2* __restrict__ pay,
                                                       const float* __restrict__ bias,
                                                       float* __restrict__ out,
                                                       int cs_shift) {
    const int tid  = threadIdx.x;
    const int lane = tid & 63;
    const int row  = blockIdx.x * 4 + (tid >> 6);
    if (row >= N_NODES) return;

    const int n = min(cnt[row << cs_shift], BIN_CAP);
    int2 p = make_int2(0, 0);
    if (lane < n) p = pay[(long)row * BIN_CAP + lane];   // one coalesced 512B load

    float acc = bias[lane];
    int k = 0;
    for (; k + 8 <= n; k += 8) {
        float g[8], v[8];
        #pragma unroll
        for (int j = 0; j < 8; ++j) {
            const int c = __shfl(p.x, k + j, 64);
            v[j] = __int_as_float(__shfl(p.y, k + j, 64));
            g[j] = support[(long)c * OUT_SIZE + lane];
        }
        #pragma unroll
        for (int j = 0; j < 8; ++j) acc += g[j] * v[j];
    }
    for (; k < n; ++k) {
        const int c = __shfl(p.x, k, 64);
        const float v = __int_as_float(__shfl(p.y, k, 64));
        acc += support[(long)c * OUT_SIZE + lane] * v;
    }
    out[(long)row * OUT_SIZE + lane] = acc;
}

// -------------------------------------------------------------------------
// Fallback tier 3: atomic scatter (only if ws can't hold pay)
// -------------------------------------------------------------------------
__global__ __launch_bounds__(256) void bias_init(float* __restrict__ out,
                                                 const float* __restrict__ bias) {
    const int i = blockIdx.x * 256 + threadIdx.x;
    if (i < N_NODES * OUT_SIZE) out[i] = bias[i & 63];
}

__global__ __launch_bounds__(256) void scatter_edges(const float* __restrict__ support,
                                                     const int* __restrict__ rows,
                                                     const int* __restrict__ cols,
                                                     const float* __restrict__ vals,
                                                     float* __restrict__ out) {
    const long gid = (long)blockIdx.x * 256 + threadIdx.x;
    if (gid >= (long)N_EDGES * 16) return;
    const int e  = (int)(gid >> 4);
    const int c4 = (int)(gid & 15) << 2;
    const int   r = rows[e];
    const int   c = cols[e];
    const float v = vals[e];
    const float4 g = *(const float4*)(support + (long)c * OUT_SIZE + c4);
    float* o = out + (long)r * OUT_SIZE + c4;
    atomicAdd(o + 0, g.x * v);
    atomicAdd(o + 1, g.y * v);
    atomicAdd(o + 2, g.z * v);
    atomicAdd(o + 3, g.w * v);
}

// -------------------------------------------------------------------------
extern "C" void kernel_launch(void* const* d_in, const int* in_sizes, int n_in,
                              void* d_out, int out_size, void* d_ws, size_t ws_size,
                              hipStream_t stream) {
    const float* x      = (const float*)d_in[0];
    const int*   rows   = (const int*)d_in[1];
    const int*   cols   = (const int*)d_in[2];
    const float* vals   = (const float*)d_in[3];
    const float* weight = (const float*)d_in[4];
    const float* bias   = (const float*)d_in[5];
    float*       out    = (float*)d_out;

    const size_t support_bytes = (size_t)N_NODES * OUT_SIZE * sizeof(float); // 12.8 MB
    const size_t pay_bytes     = (size_t)N_NODES * BIN_CAP * sizeof(int2);   // 25.6 MB

    // choose counter padding: stride 16 ints (full line) if it fits, else 4, else 1
    int cs_shift = 4;
    while (cs_shift > 0 &&
           support_bytes + (((size_t)N_NODES * sizeof(int)) << cs_shift) + pay_bytes > ws_size)
        cs_shift -= 2;
    const size_t cnt_bytes = ((size_t)N_NODES * sizeof(int)) << cs_shift;

    float* support = (float*)d_ws;
    int*   cnt     = (int*)((char*)d_ws + support_bytes);
    int2*  pay     = (int2*)((char*)d_ws + support_bytes + cnt_bytes);

    // 1) support = x @ W
    gemm_xw<<<(N_NODES + BM - 1) / BM, 256, 0, stream>>>(x, weight, support);

    if (ws_size >= support_bytes + cnt_bytes + pay_bytes) {
        hipMemsetAsync(cnt, 0, cnt_bytes, stream);
        bin_edges_pay<<<(N_EDGES / 4 + 255) / 256, 256, 0, stream>>>(rows, cols, vals,
                                                                     cnt, pay, cs_shift);
        reduce_rows_pay<<<(N_NODES + 3) / 4, 256, 0, stream>>>(support, cnt, pay,
                                                               bias, out, cs_shift);
    } else {
        bias_init<<<(N_NODES * OUT_SIZE + 255) / 256, 256, 0, stream>>>(out, bias);
        const long total = (long)N_EDGES * 16;
        scatter_edges<<<(int)((total + 255) / 256), 256, 0, stream>>>(support, rows, cols, vals, out);
    }
}

// Round 6
// 110.922 us; speedup vs baseline: 1.4007x; 1.4007x over previous
//
#include <hip/hip_runtime.h>

#define N_NODES 50000
#define N_EDGES 800000
#define IN_SIZE 128
#define OUT_SIZE 64
#define BIN_CAP 64   // max edges per row; Poisson(16) => P(>=64) ~ 2e-18

// GEMM tiling
#define BM 128       // rows per gemm block
#define KC 32        // k-chunk staged in LDS
#define KPAD 36      // row stride in LDS floats

#define G_GEMM ((N_NODES + BM - 1) / BM)     // 391 gemm blocks
#define G_BIN  ((N_EDGES / 4 + 255) / 256)   // 782 bin blocks (4 edges/thread)

// -------------------------------------------------------------------------
// Fused kernel: blocks [0, G_GEMM) do support = x @ W;
// blocks [G_GEMM, G_GEMM+G_BIN) bin (col,val) pairs by destination row.
// The two jobs touch disjoint data (x,w,support vs rows,cols,vals,cnt,pay)
// and disjoint resources (VALU/LDS vs random-access latency), so
// co-scheduling hides one under the other instead of paying serially.
// -------------------------------------------------------------------------
__global__ __launch_bounds__(256) void fused_gemm_bin(
        const float* __restrict__ x, const float* __restrict__ w,
        float* __restrict__ support,
        const int* __restrict__ rows, const int* __restrict__ cols,
        const float* __restrict__ vals,
        int* __restrict__ cnt, int2* __restrict__ pay) {
    __shared__ float xs[BM][KPAD];               // 18.4 KB
    __shared__ float wt[4][OUT_SIZE][KPAD];      // 36.9 KB  wt[kc][c][k&31] = w[k][c]
    const int tid = threadIdx.x;

    if (blockIdx.x < G_GEMM) {
        // ================= GEMM path =================
        const int row0 = blockIdx.x * BM;

        #pragma unroll
        for (int i = 0; i < 8; ++i) {
            const int f  = tid + 256 * i;            // f < 2048
            const int k  = f >> 4;                   // 0..127
            const int c0 = (f & 15) << 2;            // 0..60
            const float4 wv = ((const float4*)w)[f];
            wt[k >> 5][c0 + 0][k & 31] = wv.x;
            wt[k >> 5][c0 + 1][k & 31] = wv.y;
            wt[k >> 5][c0 + 2][k & 31] = wv.z;
            wt[k >> 5][c0 + 3][k & 31] = wv.w;
        }

        float4 xreg[4];
        #pragma unroll
        for (int i = 0; i < 4; ++i) {
            const int f = tid + 256 * i;             // row=f>>3, koff=(f&7)*4
            int r = row0 + (f >> 3);
            if (r >= N_NODES) r = N_NODES - 1;
            xreg[i] = *(const float4*)(x + (long)r * IN_SIZE + ((f & 7) << 2));
        }

        const int rg = tid & 15;
        const int c0 = (tid >> 4) << 2;
        float4 acc[8];
        #pragma unroll
        for (int i = 0; i < 8; ++i) acc[i] = make_float4(0.f, 0.f, 0.f, 0.f);

        for (int kc = 0; kc < 4; ++kc) {
            __syncthreads();
            #pragma unroll
            for (int i = 0; i < 4; ++i) {
                const int f = tid + 256 * i;
                *(float4*)&xs[f >> 3][(f & 7) << 2] = xreg[i];
            }
            __syncthreads();
            if (kc < 3) {
                #pragma unroll
                for (int i = 0; i < 4; ++i) {
                    const int f = tid + 256 * i;
                    int r = row0 + (f >> 3);
                    if (r >= N_NODES) r = N_NODES - 1;
                    xreg[i] = *(const float4*)(x + (long)r * IN_SIZE + (kc + 1) * KC + ((f & 7) << 2));
                }
            }
            #pragma unroll
            for (int k4 = 0; k4 < 8; ++k4) {
                const float4 w0 = *(const float4*)&wt[kc][c0 + 0][k4 << 2];
                const float4 w1 = *(const float4*)&wt[kc][c0 + 1][k4 << 2];
                const float4 w2 = *(const float4*)&wt[kc][c0 + 2][k4 << 2];
                const float4 w3 = *(const float4*)&wt[kc][c0 + 3][k4 << 2];
                #pragma unroll
                for (int i = 0; i < 8; ++i) {
                    const float4 xv = *(const float4*)&xs[rg + (i << 4)][k4 << 2];
                    acc[i].x += xv.x * w0.x + xv.y * w0.y + xv.z * w0.z + xv.w * w0.w;
                    acc[i].y += xv.x * w1.x + xv.y * w1.y + xv.z * w1.z + xv.w * w1.w;
                    acc[i].z += xv.x * w2.x + xv.y * w2.y + xv.z * w2.z + xv.w * w2.w;
                    acc[i].w += xv.x * w3.x + xv.y * w3.y + xv.z * w3.z + xv.w * w3.w;
                }
            }
        }

        #pragma unroll
        for (int i = 0; i < 8; ++i) {
            const int r = row0 + rg + (i << 4);
            if (r < N_NODES)
                *(float4*)(support + (long)r * OUT_SIZE + c0) = acc[i];
        }
    } else {
        // ================= BIN path =================
        const int i  = (blockIdx.x - G_GEMM) * 256 + tid;
        const int e0 = i * 4;
        if (e0 + 4 <= N_EDGES) {
            const int4   r4 = ((const int4*)rows)[i];
            const int4   c4 = ((const int4*)cols)[i];
            const float4 v4 = ((const float4*)vals)[i];
            int s;
            s = atomicAdd(&cnt[r4.x], 1); if (s < BIN_CAP) pay[r4.x * BIN_CAP + s] = make_int2(c4.x, __float_as_int(v4.x));
            s = atomicAdd(&cnt[r4.y], 1); if (s < BIN_CAP) pay[r4.y * BIN_CAP + s] = make_int2(c4.y, __float_as_int(v4.y));
            s = atomicAdd(&cnt[r4.z], 1); if (s < BIN_CAP) pay[r4.z * BIN_CAP + s] = make_int2(c4.z, __float_as_int(v4.z));
            s = atomicAdd(&cnt[r4.w], 1); if (s < BIN_CAP) pay[r4.w * BIN_CAP + s] = make_int2(c4.w, __float_as_int(v4.w));
        } else {
            for (int e = e0; e < N_EDGES; ++e) {
                const int r = rows[e];
                const int s = atomicAdd(&cnt[r], 1);
                if (s < BIN_CAP) pay[r * BIN_CAP + s] = make_int2(cols[e], __float_as_int(vals[e]));
            }
        }
    }
}

// -------------------------------------------------------------------------
// Per-row gather-reduce, ILP-pipelined (8-deep).
// -------------------------------------------------------------------------
__global__ __launch_bounds__(256) void reduce_rows_pay(const float* __restrict__ support,
                                                       const int* __restrict__ cnt,
                                                       const int2* __restrict__ pay,
                                                       const float* __restrict__ bias,
                                                       float* __restrict__ out) {
    const int tid  = threadIdx.x;
    const int lane = tid & 63;
    const int row  = blockIdx.x * 4 + (tid >> 6);
    if (row >= N_NODES) return;

    const int n = min(cnt[row], BIN_CAP);
    int2 p = make_int2(0, 0);
    if (lane < n) p = pay[(long)row * BIN_CAP + lane];   // one coalesced 512B load

    float acc = bias[lane];
    int k = 0;
    for (; k + 8 <= n; k += 8) {
        float g[8], v[8];
        #pragma unroll
        for (int j = 0; j < 8; ++j) {
            const int c = __shfl(p.x, k + j, 64);
            v[j] = __int_as_float(__shfl(p.y, k + j, 64));
            g[j] = support[(long)c * OUT_SIZE + lane];
        }
        #pragma unroll
        for (int j = 0; j < 8; ++j) acc += g[j] * v[j];
    }
    for (; k < n; ++k) {
        const int c = __shfl(p.x, k, 64);
        const float v = __int_as_float(__shfl(p.y, k, 64));
        acc += support[(long)c * OUT_SIZE + lane] * v;
    }
    out[(long)row * OUT_SIZE + lane] = acc;
}

// -------------------------------------------------------------------------
// Fallback tier (small ws): separate gemm + atomic scatter
// -------------------------------------------------------------------------
__global__ __launch_bounds__(256) void gemm_xw(const float* __restrict__ x,
                                               const float* __restrict__ w,
                                               float* __restrict__ support) {
    __shared__ float wlds[IN_SIZE][OUT_SIZE];
    const int tid = threadIdx.x;
    const float4* w4 = (const float4*)w;
    float4* wl4 = (float4*)&wlds[0][0];
    #pragma unroll
    for (int i = 0; i < (IN_SIZE * OUT_SIZE / 4) / 256; ++i)
        wl4[tid + i * 256] = w4[tid + i * 256];
    __syncthreads();
    const int col = tid & 63;
    const long row = (long)blockIdx.x * 4 + (tid >> 6);
    if (row >= N_NODES) return;
    const float4* xr = (const float4*)(x + row * IN_SIZE);
    float acc = 0.f;
    #pragma unroll
    for (int k4 = 0; k4 < IN_SIZE / 4; ++k4) {
        float4 xv = xr[k4];
        acc += xv.x * wlds[k4 * 4 + 0][col];
        acc += xv.y * wlds[k4 * 4 + 1][col];
        acc += xv.z * wlds[k4 * 4 + 2][col];
        acc += xv.w * wlds[k4 * 4 + 3][col];
    }
    support[row * OUT_SIZE + col] = acc;
}

__global__ __launch_bounds__(256) void bias_init(float* __restrict__ out,
                                                 const float* __restrict__ bias) {
    const int i = blockIdx.x * 256 + threadIdx.x;
    if (i < N_NODES * OUT_SIZE) out[i] = bias[i & 63];
}

__global__ __launch_bounds__(256) void scatter_edges(const float* __restrict__ support,
                                                     const int* __restrict__ rows,
                                                     const int* __restrict__ cols,
                                                     const float* __restrict__ vals,
                                                     float* __restrict__ out) {
    const long gid = (long)blockIdx.x * 256 + threadIdx.x;
    if (gid >= (long)N_EDGES * 16) return;
    const int e  = (int)(gid >> 4);
    const int c4 = (int)(gid & 15) << 2;
    const int   r = rows[e];
    const int   c = cols[e];
    const float v = vals[e];
    const float4 g = *(const float4*)(support + (long)c * OUT_SIZE + c4);
    float* o = out + (long)r * OUT_SIZE + c4;
    atomicAdd(o + 0, g.x * v);
    atomicAdd(o + 1, g.y * v);
    atomicAdd(o + 2, g.z * v);
    atomicAdd(o + 3, g.w * v);
}

// -------------------------------------------------------------------------
extern "C" void kernel_launch(void* const* d_in, const int* in_sizes, int n_in,
                              void* d_out, int out_size, void* d_ws, size_t ws_size,
                              hipStream_t stream) {
    const float* x      = (const float*)d_in[0];
    const int*   rows   = (const int*)d_in[1];
    const int*   cols   = (const int*)d_in[2];
    const float* vals   = (const float*)d_in[3];
    const float* weight = (const float*)d_in[4];
    const float* bias   = (const float*)d_in[5];
    float*       out    = (float*)d_out;

    const size_t support_bytes = (size_t)N_NODES * OUT_SIZE * sizeof(float); // 12.8 MB
    const size_t cnt_bytes     = (size_t)N_NODES * sizeof(int);              // 0.2 MB
    const size_t pay_bytes     = (size_t)N_NODES * BIN_CAP * sizeof(int2);   // 25.6 MB

    float* support = (float*)d_ws;
    int*   cnt     = (int*)((char*)d_ws + support_bytes);
    int2*  pay     = (int2*)((char*)d_ws + support_bytes + cnt_bytes);

    if (ws_size >= support_bytes + cnt_bytes + pay_bytes) {
        hipMemsetAsync(cnt, 0, cnt_bytes, stream);
        fused_gemm_bin<<<G_GEMM + G_BIN, 256, 0, stream>>>(x, weight, support,
                                                           rows, cols, vals, cnt, pay);
        reduce_rows_pay<<<(N_NODES + 3) / 4, 256, 0, stream>>>(support, cnt, pay, bias, out);
    } else {
        gemm_xw<<<(N_NODES + 3) / 4, 256, 0, stream>>>(x, weight, support);
        bias_init<<<(N_NODES * OUT_SIZE + 255) / 256, 256, 0, stream>>>(out, bias);
        const long total = (long)N_EDGES * 16;
        scatter_edges<<<(int)((total + 255) / 256), 256, 0, stream>>>(support, rows, cols, vals, out);
    }
}